// Round 1
// baseline (1006.411 us; speedup 1.0000x reference)
//
#include <hip/hip_runtime.h>
#include <stdint.h>

// Problem constants
#define MM 32768
#define KK 1024
#define NN 4096

#define BM 128
#define BN 128
#define BK 64

typedef __attribute__((ext_vector_type(4))) float floatx4;
typedef long i64;

// ---- fp8 e4m3fn pack via HW cvt (RNE, OCP on gfx950) ----
__device__ __forceinline__ uint32_t pack4_fp8(float a, float b, float c, float d) {
  int v = 0;
  v = __builtin_amdgcn_cvt_pk_fp8_f32(a, b, v, false);  // bytes 0,1
  v = __builtin_amdgcn_cvt_pk_fp8_f32(c, d, v, true);   // bytes 2,3
  return (uint32_t)v;
}

// ---- async global->LDS, 16B per lane ----
__device__ __forceinline__ void gld_lds16(const void* g, void* l) {
  __builtin_amdgcn_global_load_lds(
      (const __attribute__((address_space(1))) uint32_t*)g,
      (__attribute__((address_space(3))) uint32_t*)l, 16, 0, 0);
}

// ---- quantize x: M*K fp32 -> fp8, 16 elems/thread ----
__global__ __launch_bounds__(256) void quant_x_kernel(const float* __restrict__ x,
                                                      uint8_t* __restrict__ o) {
  size_t i = ((size_t)blockIdx.x * 256 + threadIdx.x) * 16;
  const float4* xp = (const float4*)(x + i);
  float4 f0 = xp[0], f1 = xp[1], f2 = xp[2], f3 = xp[3];
  uint4 o4;
  o4.x = pack4_fp8(f0.x, f0.y, f0.z, f0.w);
  o4.y = pack4_fp8(f1.x, f1.y, f1.z, f1.w);
  o4.z = pack4_fp8(f2.x, f2.y, f2.z, f2.w);
  o4.w = pack4_fp8(f3.x, f3.y, f3.z, f3.w);
  *(uint4*)(o + i) = o4;
}

// ---- quantize + transpose w: (K,N) fp32 -> (N,K) fp8 ----
// grid: (N/256, K/16); coalesced column reads, 16B row writes.
__global__ __launch_bounds__(256) void quant_w_kernel(const float* __restrict__ w,
                                                      uint8_t* __restrict__ o) {
  int n  = blockIdx.x * 256 + threadIdx.x;
  int k0 = blockIdx.y * 16;
  uint32_t p[4];
#pragma unroll
  for (int q = 0; q < 4; ++q) {
    float a = w[(size_t)(k0 + q * 4 + 0) * NN + n];
    float b = w[(size_t)(k0 + q * 4 + 1) * NN + n];
    float c = w[(size_t)(k0 + q * 4 + 2) * NN + n];
    float d = w[(size_t)(k0 + q * 4 + 3) * NN + n];
    p[q] = pack4_fp8(a, b, c, d);
  }
  *(uint4*)(o + (size_t)n * KK + k0) = make_uint4(p[0], p[1], p[2], p[3]);
}

// ---- fp8 GEMM: C(M,N) = A8(M,K) * B8T(N,K)^T, fp32 out ----
// 128x128 tile / block of 256 threads (4 waves, each 64x64 = 4x4 MFMA tiles)
__global__ __launch_bounds__(256) void gemm_fp8_kernel(const uint8_t* __restrict__ A,
                                                       const uint8_t* __restrict__ Bt,
                                                       float* __restrict__ C) {
  __shared__ uint8_t As[BM * BK];  // [m][k] 8 KB
  __shared__ uint8_t Bs[BN * BK];  // [n][k] 8 KB

  const int tid  = threadIdx.x;
  const int lane = tid & 63;
  const int wv   = tid >> 6;
  const int wr   = (wv >> 1) * 64;  // wave row offset in tile
  const int wc   = (wv & 1) * 64;   // wave col offset in tile
  const int quad = lane >> 4;
  const int r    = lane & 15;

  const long bm = (long)blockIdx.y * BM;
  const long bn = (long)blockIdx.x * BN;

  // staging: thread t loads 16B at LDS offset t*16 (wave-uniform base + lane*16)
  const int srow = tid >> 2;         // 0..63
  const int scol = (tid & 3) << 4;   // 0,16,32,48
  const uint8_t* Ag = A + (bm + srow) * KK + scol;
  const uint8_t* Bg = Bt + (bn + srow) * KK + scol;
  uint8_t* Al = &As[tid * 16];
  uint8_t* Bl = &Bs[tid * 16];

  floatx4 acc[4][4] = {};

  for (int k0 = 0; k0 < KK; k0 += BK) {
    gld_lds16(Ag + k0, Al);
    gld_lds16(Ag + 64 * KK + k0, Al + 4096);
    gld_lds16(Bg + k0, Bl);
    gld_lds16(Bg + 64 * KK + k0, Bl + 4096);
    __syncthreads();  // compiler emits vmcnt(0) drain before s_barrier

#pragma unroll
    for (int kk = 0; kk < 2; ++kk) {
      i64 af[4], bf[4];
#pragma unroll
      for (int i = 0; i < 4; ++i)
        af[i] = *(const i64*)&As[(wr + i * 16 + r) * BK + kk * 32 + quad * 8];
#pragma unroll
      for (int j = 0; j < 4; ++j)
        bf[j] = *(const i64*)&Bs[(wc + j * 16 + r) * BK + kk * 32 + quad * 8];
#pragma unroll
      for (int i = 0; i < 4; ++i)
#pragma unroll
        for (int j = 0; j < 4; ++j)
          acc[i][j] = __builtin_amdgcn_mfma_f32_16x16x32_fp8_fp8(af[i], bf[j], acc[i][j], 0, 0, 0);
    }
    __syncthreads();
  }

  // epilogue: C/D layout col=lane&15, row=quad*4+reg (dtype-independent, m121-128)
#pragma unroll
  for (int i = 0; i < 4; ++i) {
    const long row0 = bm + wr + i * 16 + quad * 4;
#pragma unroll
    for (int j = 0; j < 4; ++j) {
      const long col = bn + wc + j * 16 + r;
#pragma unroll
      for (int v = 0; v < 4; ++v) C[(row0 + v) * NN + col] = acc[i][j][v];
    }
  }
}

extern "C" void kernel_launch(void* const* d_in, const int* in_sizes, int n_in,
                              void* d_out, int out_size, void* d_ws, size_t ws_size,
                              hipStream_t stream) {
  const float* x = (const float*)d_in[0];  // (M,K) fp32
  const float* w = (const float*)d_in[1];  // (K,N) fp32
  float* out = (float*)d_out;              // (M,N) fp32

  uint8_t* x8  = (uint8_t*)d_ws;                    // 32 MB
  uint8_t* w8t = x8 + (size_t)MM * KK;              // 4 MB, (N,K)

  quant_x_kernel<<<(MM * (size_t)KK) / (256 * 16), 256, 0, stream>>>(x, x8);
  quant_w_kernel<<<dim3(NN / 256, KK / 16), 256, 0, stream>>>(w, w8t);
  gemm_fp8_kernel<<<dim3(NN / BN, MM / BM), 256, 0, stream>>>(x8, w8t, out);
}